// Round 7
// baseline (366.476 us; speedup 1.0000x reference)
//
#include <hip/hip_runtime.h>
#include <hip/hip_fp16.h>
#include <cstdint>
#include <cstddef>

// GCN_EW: 2-layer GCN with exp edge weights, gcn_norm w/ self-loops,
// training-mode BN, final 64->1 projection.
// B=2, N=50000, E=800000, IN=128, HID=64.
//
// R7: (1) mega-kernel fuses k_fill (atomic-pipe-bound, VALU 1.5%) with
// layer-1 GEMM (VALU-bound) -- independent work, role-striped blocks 1:2,
// the two regimes overlap on each CU. (2) pairs packed to 4 B:
// (src<<16)|fp16(expw) (src<65536). (3) k_agg 12+4-deep unroll.
// (4) k_scale folded into k_stats via fence+counter last-block.
// Row order downstream is r = node*2 + b (batch-fused gather).

#define CAP  64
#define OCAP 65536
#define BN_EPS 1e-5f

static __device__ __forceinline__ unsigned h2u(__half2 h) {
  union { __half2 h; unsigned u; } c; c.h = h; return c.u;
}
static __device__ __forceinline__ __half2 u2h(unsigned u) {
  union { unsigned u; __half2 h; } c; c.u = u; return c.h;
}
static __device__ __forceinline__ unsigned pack_pair(int src, float w) {
  __half hw = __float2half_rn(w);
  union { __half h; unsigned short s; } c; c.h = hw;
  return ((unsigned)src << 16) | c.s;
}
static __device__ __forceinline__ float pair_w(unsigned p) {
  union { unsigned short s; __half h; } c; c.s = (unsigned short)(p & 0xFFFFu);
  return __half2float(c.h);
}

// ---- mega: role-striped fill (1 edge/thread) + layer-1 GEMM ----
// gemm: out[orow,64](fp16) = in[gr,128] @ W[128,64], orow = node*2+b perm.
// 64 rows/block, KC=64 chunks: ws 16KB + xs 17.4KB LDS.
__global__ void k_mega(const float* __restrict__ x, const float* __restrict__ W,
                       __half* __restrict__ out, int nrows, int N,
                       const float* __restrict__ ew, const int* __restrict__ ei,
                       int* __restrict__ cnt, unsigned* __restrict__ pairs,
                       int* __restrict__ ofl_cnt, int* __restrict__ ofl_list,
                       int E, int gemmBlocks, int fillBlocks) {
  constexpr int RT = 64, KC = 64, S = KC + 4;
  __shared__ float ws[KC * 64];
  __shared__ float xs[RT * S];

  int bid = blockIdx.x;
  int tid = threadIdx.x;
  int role = bid % 3;

  if (role == 0) {
    int gid = bid / 3;
    if (gid >= gemmBlocks) return;
    int row0 = gid * RT;
    int rg = tid >> 4, cg = tid & 15;
    int c0 = cg * 4, r0 = rg * 4;
    float acc[4][4];
#pragma unroll
    for (int i = 0; i < 4; ++i)
#pragma unroll
      for (int j = 0; j < 4; ++j) acc[i][j] = 0.0f;

    for (int ch = 0; ch < 2; ++ch) {       // CIN = 128 = 2 chunks
      if (ch) __syncthreads();
      const float4* Wp = (const float4*)(W + (size_t)ch * KC * 64);
      for (int s = tid; s < KC * 16; s += 256)
        ((float4*)ws)[s] = Wp[s];
      for (int s = tid; s < RT * 16; s += 256) {
        int r = s >> 4, k4 = s & 15;
        int gr = row0 + r;
        float4 v = make_float4(0.f, 0.f, 0.f, 0.f);
        if (gr < nrows)
          v = *(const float4*)(x + (size_t)gr * 128 + ch * KC + k4 * 4);
        *(float4*)&xs[r * S + k4 * 4] = v;
      }
      __syncthreads();
#pragma unroll 2
      for (int kk = 0; kk < KC; kk += 4) {
        float4 wv0 = *(const float4*)&ws[(kk + 0) * 64 + c0];
        float4 wv1 = *(const float4*)&ws[(kk + 1) * 64 + c0];
        float4 wv2 = *(const float4*)&ws[(kk + 2) * 64 + c0];
        float4 wv3 = *(const float4*)&ws[(kk + 3) * 64 + c0];
#pragma unroll
        for (int i = 0; i < 4; ++i) {
          float4 xv = *(const float4*)&xs[(r0 + i) * S + kk];
          acc[i][0] = fmaf(xv.x, wv0.x, acc[i][0]);
          acc[i][1] = fmaf(xv.x, wv0.y, acc[i][1]);
          acc[i][2] = fmaf(xv.x, wv0.z, acc[i][2]);
          acc[i][3] = fmaf(xv.x, wv0.w, acc[i][3]);
          acc[i][0] = fmaf(xv.y, wv1.x, acc[i][0]);
          acc[i][1] = fmaf(xv.y, wv1.y, acc[i][1]);
          acc[i][2] = fmaf(xv.y, wv1.z, acc[i][2]);
          acc[i][3] = fmaf(xv.y, wv1.w, acc[i][3]);
          acc[i][0] = fmaf(xv.z, wv2.x, acc[i][0]);
          acc[i][1] = fmaf(xv.z, wv2.y, acc[i][1]);
          acc[i][2] = fmaf(xv.z, wv2.z, acc[i][2]);
          acc[i][3] = fmaf(xv.z, wv2.w, acc[i][3]);
          acc[i][0] = fmaf(xv.w, wv3.x, acc[i][0]);
          acc[i][1] = fmaf(xv.w, wv3.y, acc[i][1]);
          acc[i][2] = fmaf(xv.w, wv3.z, acc[i][2]);
          acc[i][3] = fmaf(xv.w, wv3.w, acc[i][3]);
        }
      }
    }
#pragma unroll
    for (int i = 0; i < 4; ++i) {
      int gr = row0 + r0 + i;
      if (gr < nrows) {
        int orow = (gr < N) ? gr * 2 : (gr - N) * 2 + 1;
        __half2 h01 = __floats2half2_rn(acc[i][0], acc[i][1]);
        __half2 h23 = __floats2half2_rn(acc[i][2], acc[i][3]);
        *(uint2*)(out + (size_t)orow * 64 + c0) = make_uint2(h2u(h01), h2u(h23));
      }
    }
  } else {
    int fid = (bid / 3) * 2 + role - 1;
    if (fid >= fillBlocks) return;
    int e = fid * 256 + tid;
    if (e >= E) return;
    int r = ei[e];
    int c = ei[(size_t)E + e];
    float w = expf(ew[e]);
    int pos = atomicAdd(&cnt[c], 1);
    if (pos < CAP) {
      pairs[(size_t)c * CAP + pos] = pack_pair(r, w);
    } else {
      int o = atomicAdd(ofl_cnt, 1);
      if (o < OCAP) ofl_list[o] = e;
    }
  }
}

// deg[node] = 1 + sum of expw over its bucket (one wave per node).
__global__ void k_degb(const unsigned* __restrict__ pairs, const int* __restrict__ cnt,
                       float* __restrict__ deg, int N) {
  int node = blockIdx.x * 4 + (threadIdx.x >> 6);
  if (node >= N) return;
  int lane = threadIdx.x & 63;
  int n = cnt[node];
  n = n > CAP ? CAP : n;
  float v = 0.0f;
  if (lane < n) v = pair_w(pairs[(size_t)node * CAP + lane]);
#pragma unroll
  for (int off = 32; off > 0; off >>= 1) v += __shfl_xor(v, off, 64);
  if (lane == 0) deg[node] = v + 1.0f;
}

// overflow edges' contribution to deg (expected zero iterations)
__global__ void k_dego(const float* __restrict__ ew, const int* __restrict__ ei,
                       const int* __restrict__ ofl_cnt, const int* __restrict__ ofl_list,
                       float* __restrict__ deg, int E) {
  int tot = *ofl_cnt;
  if (tot > OCAP) tot = OCAP;
  for (int i = blockIdx.x * blockDim.x + threadIdx.x; i < tot;
       i += gridDim.x * blockDim.x) {
    int e = ofl_list[i];
    atomicAdd(&deg[ei[(size_t)E + e]], expf(ew[e]));
  }
}

__global__ void k_dinvf(float* __restrict__ deg, int N) {
  int i = blockIdx.x * blockDim.x + threadIdx.x;
  if (i < N) deg[i] = rsqrtf(deg[i]);
}

// layer-2 GEMM: out[r,64](fp16) = bn1(relu(in+b1))[r,64] @ W[64,64]
__global__ void k_gemm2(const __half* __restrict__ in, const float* __restrict__ W,
                        __half* __restrict__ out, int nrows,
                        const float* __restrict__ bias, const float* __restrict__ scsh) {
  constexpr int RT = 64, KC = 64, S = KC + 4;
  __shared__ float ws[KC * 64];
  __shared__ float xs[RT * S];

  int tid = threadIdx.x;
  int row0 = blockIdx.x * RT;
  for (int s = tid; s < KC * 16; s += 256)
    ((float4*)ws)[s] = ((const float4*)W)[s];
  for (int s = tid; s < RT * 16; s += 256) {
    int r = s >> 4, k4 = s & 15;
    int gr = row0 + r;
    int kg = k4 * 4;
    float4 v = make_float4(0.f, 0.f, 0.f, 0.f);
    if (gr < nrows) {
      uint2 u = *(const uint2*)(in + (size_t)gr * 64 + kg);
      float2 fa = __half22float2(u2h(u.x));
      float2 fb = __half22float2(u2h(u.y));
      v = make_float4(fa.x, fa.y, fb.x, fb.y);
    }
    float4 bb = *(const float4*)(bias + kg);
    float4 sc = *(const float4*)(scsh + kg);
    float4 sh = *(const float4*)(scsh + 64 + kg);
    v.x = fmaxf(v.x + bb.x, 0.f) * sc.x + sh.x;
    v.y = fmaxf(v.y + bb.y, 0.f) * sc.y + sh.y;
    v.z = fmaxf(v.z + bb.z, 0.f) * sc.z + sh.z;
    v.w = fmaxf(v.w + bb.w, 0.f) * sc.w + sh.w;
    *(float4*)&xs[r * S + kg] = v;
  }
  __syncthreads();

  int rg = tid >> 4, cg = tid & 15;
  int c0 = cg * 4, r0 = rg * 4;
  float acc[4][4];
#pragma unroll
  for (int i = 0; i < 4; ++i)
#pragma unroll
    for (int j = 0; j < 4; ++j) acc[i][j] = 0.0f;
#pragma unroll 2
  for (int kk = 0; kk < KC; kk += 4) {
    float4 wv0 = *(const float4*)&ws[(kk + 0) * 64 + c0];
    float4 wv1 = *(const float4*)&ws[(kk + 1) * 64 + c0];
    float4 wv2 = *(const float4*)&ws[(kk + 2) * 64 + c0];
    float4 wv3 = *(const float4*)&ws[(kk + 3) * 64 + c0];
#pragma unroll
    for (int i = 0; i < 4; ++i) {
      float4 xv = *(const float4*)&xs[(r0 + i) * S + kk];
      acc[i][0] = fmaf(xv.x, wv0.x, acc[i][0]);
      acc[i][1] = fmaf(xv.x, wv0.y, acc[i][1]);
      acc[i][2] = fmaf(xv.x, wv0.z, acc[i][2]);
      acc[i][3] = fmaf(xv.x, wv0.w, acc[i][3]);
      acc[i][0] = fmaf(xv.y, wv1.x, acc[i][0]);
      acc[i][1] = fmaf(xv.y, wv1.y, acc[i][1]);
      acc[i][2] = fmaf(xv.y, wv1.z, acc[i][2]);
      acc[i][3] = fmaf(xv.y, wv1.w, acc[i][3]);
      acc[i][0] = fmaf(xv.z, wv2.x, acc[i][0]);
      acc[i][1] = fmaf(xv.z, wv2.y, acc[i][1]);
      acc[i][2] = fmaf(xv.z, wv2.z, acc[i][2]);
      acc[i][3] = fmaf(xv.z, wv2.w, acc[i][3]);
      acc[i][0] = fmaf(xv.w, wv3.x, acc[i][0]);
      acc[i][1] = fmaf(xv.w, wv3.y, acc[i][1]);
      acc[i][2] = fmaf(xv.w, wv3.z, acc[i][2]);
      acc[i][3] = fmaf(xv.w, wv3.w, acc[i][3]);
    }
  }
#pragma unroll
  for (int i = 0; i < 4; ++i) {
    int gr = row0 + r0 + i;
    if (gr < nrows) {
      __half2 h01 = __floats2half2_rn(acc[i][0], acc[i][1]);
      __half2 h23 = __floats2half2_rn(acc[i][2], acc[i][3]);
      *(uint2*)(out + (size_t)gr * 64 + c0) = make_uint2(h2u(h01), h2u(h23));
    }
  }
}

// One wave per node; lane = half2 (2 of 128 batch-fused channels).
// raw = dinv_c*(dinv_c*self + sum expw_k*dinv_rk*h_rk). 12+4-deep unroll.
__global__ void k_agg(const __half* __restrict__ h, const unsigned* __restrict__ pairs,
                      const int* __restrict__ cnt, const float* __restrict__ dinv,
                      __half* __restrict__ raw, int N) {
  int node = blockIdx.x * 4 + (threadIdx.x >> 6);
  if (node >= N) return;
  int lane = threadIdx.x & 63;
  const __half2* hv = (const __half2*)h;
  float dc = dinv[node];
  float2 self = __half22float2(hv[(size_t)node * 64 + lane]);
  float2 acc = make_float2(self.x * dc, self.y * dc);
  int n = cnt[node];
  n = n > CAP ? CAP : n;
  const unsigned* pp = pairs + (size_t)node * CAP;
  int k = 0;
  for (; k + 12 <= n; k += 12) {
    unsigned p[12];
#pragma unroll
    for (int q = 0; q < 12; ++q) p[q] = pp[k + q];
    float dr[12];
#pragma unroll
    for (int q = 0; q < 12; ++q) dr[q] = dinv[p[q] >> 16];
    __half2 v[12];
#pragma unroll
    for (int q = 0; q < 12; ++q) v[q] = hv[(size_t)(p[q] >> 16) * 64 + lane];
#pragma unroll
    for (int q = 0; q < 12; ++q) {
      float w = pair_w(p[q]) * dr[q];
      float2 f = __half22float2(v[q]);
      acc.x = fmaf(w, f.x, acc.x);
      acc.y = fmaf(w, f.y, acc.y);
    }
  }
  for (; k + 4 <= n; k += 4) {
    unsigned p[4];
#pragma unroll
    for (int q = 0; q < 4; ++q) p[q] = pp[k + q];
    float dr[4];
#pragma unroll
    for (int q = 0; q < 4; ++q) dr[q] = dinv[p[q] >> 16];
    __half2 v[4];
#pragma unroll
    for (int q = 0; q < 4; ++q) v[q] = hv[(size_t)(p[q] >> 16) * 64 + lane];
#pragma unroll
    for (int q = 0; q < 4; ++q) {
      float w = pair_w(p[q]) * dr[q];
      float2 f = __half22float2(v[q]);
      acc.x = fmaf(w, f.x, acc.x);
      acc.y = fmaf(w, f.y, acc.y);
    }
  }
  for (; k < n; ++k) {
    unsigned p = pp[k];
    float w = pair_w(p) * dinv[p >> 16];
    float2 f = __half22float2(hv[(size_t)(p >> 16) * 64 + lane]);
    acc.x = fmaf(w, f.x, acc.x);
    acc.y = fmaf(w, f.y, acc.y);
  }
  ((__half2*)raw)[(size_t)node * 64 + lane] =
      __floats2half2_rn(acc.x * dc, acc.y * dc);
}

// Exact fallback for bucket overflow (expected empty). CAS on packed half2.
__global__ void k_ofl(const float* __restrict__ ew, const int* __restrict__ ei,
                      const float* __restrict__ dinv, const int* __restrict__ ofl_cnt,
                      const int* __restrict__ ofl_list,
                      const __half* __restrict__ h, __half* __restrict__ raw,
                      int N, int E) {
  int tot = *ofl_cnt;
  if (tot > OCAP) tot = OCAP;
  for (int i = blockIdx.x * blockDim.x + threadIdx.x; i < tot;
       i += gridDim.x * blockDim.x) {
    int e = ofl_list[i];
    int r = ei[e];
    int c = ei[(size_t)E + e];
    float nrm = dinv[r] * expf(ew[e]) * dinv[c];
    const __half2* hr = (const __half2*)(h + (size_t)r * 128);
    unsigned* dst = (unsigned*)(raw + (size_t)c * 128);
    for (int j = 0; j < 64; ++j) {
      float2 hv2 = __half22float2(hr[j]);
      unsigned old = dst[j], assumed;
      do {
        assumed = old;
        float2 cur = __half22float2(u2h(assumed));
        __half2 nv = __floats2half2_rn(cur.x + nrm * hv2.x, cur.y + nrm * hv2.y);
        old = atomicCAS(&dst[j], assumed, h2u(nv));
      } while (old != assumed);
    }
  }
}

// BN sums over y = relu(raw + bias); last block computes scale/shift.
__global__ void k_stats(const __half* __restrict__ raw, const float* __restrict__ bias,
                        float* __restrict__ stats, const float* __restrict__ g,
                        const float* __restrict__ be, float* __restrict__ scsh,
                        int* __restrict__ done, float invCnt, int rows) {
  __shared__ float S[256], Q[256];
  __shared__ int isLast;
  int tid = threadIdx.x;
  int c = tid & 63, rg = tid >> 6;
  float s = 0.0f, q = 0.0f;
  for (int r = blockIdx.x * 4 + rg; r < rows; r += gridDim.x * 4) {
    float y = fmaxf(__half2float(raw[(size_t)r * 64 + c]) + bias[c], 0.0f);
    s += y;
    q += y * y;
  }
  S[tid] = s; Q[tid] = q;
  __syncthreads();
  if (tid < 64) {
    float ts = S[tid] + S[tid + 64] + S[tid + 128] + S[tid + 192];
    float tq = Q[tid] + Q[tid + 64] + Q[tid + 128] + Q[tid + 192];
    atomicAdd(&stats[tid], ts);
    atomicAdd(&stats[64 + tid], tq);
  }
  __threadfence();
  if (tid == 0) {
    int old = atomicAdd(done, 1);
    isLast = (old == (int)gridDim.x - 1);
  }
  __syncthreads();
  if (isLast && tid < 64) {
    __threadfence();
    float m = atomicAdd(&stats[tid], 0.0f) * invCnt;        // coherent read
    float qq = atomicAdd(&stats[64 + tid], 0.0f) * invCnt;
    float v = qq - m * m;
    v = v < 0.0f ? 0.0f : v;
    float inv = rsqrtf(v + BN_EPS);
    float sc = g[tid] * inv;
    scsh[tid] = sc;
    scsh[64 + tid] = be[tid] - m * sc;
  }
}

// rows are (node,b): r -> out[b*N + node]
__global__ void k_out(const __half* __restrict__ raw, const float* __restrict__ bias,
                      const float* __restrict__ scsh, const float* __restrict__ Wc,
                      const float* __restrict__ bc, float* __restrict__ out,
                      int rows, int N) {
  int row = blockIdx.x * 4 + (threadIdx.x >> 6);
  int c = threadIdx.x & 63;
  if (row >= rows) return;
  float v = fmaxf(__half2float(raw[(size_t)row * 64 + c]) + bias[c], 0.0f)
              * scsh[c] + scsh[64 + c];
  float p = v * Wc[c];
#pragma unroll
  for (int off = 32; off > 0; off >>= 1) p += __shfl_xor(p, off, 64);
  if (c == 0) {
    int node = row >> 1, b = row & 1;
    out[(size_t)b * N + node] = p + bc[0];
  }
}

extern "C" void kernel_launch(void* const* d_in, const int* in_sizes, int n_in,
                              void* d_out, int out_size, void* d_ws, size_t ws_size,
                              hipStream_t stream) {
  const float* x   = (const float*)d_in[0];
  const float* ew  = (const float*)d_in[1];
  const float* W1  = (const float*)d_in[2];
  const float* b1  = (const float*)d_in[3];
  const float* W2  = (const float*)d_in[4];
  const float* b2  = (const float*)d_in[5];
  const float* g1  = (const float*)d_in[6];
  const float* be1 = (const float*)d_in[7];
  const float* g2  = (const float*)d_in[8];
  const float* be2 = (const float*)d_in[9];
  const float* Wc  = (const float*)d_in[10];
  const float* bc  = (const float*)d_in[11];
  const int*   ei  = (const int*)d_in[12];

  const int E  = in_sizes[1];
  const int BN = in_sizes[0] / 128;  // B*N = 100000
  const int N  = BN / 2;

  char* w = (char*)d_ws;
  size_t off = 0;
  int*   cnt    = (int*)  (w + off); off += (size_t)N * 4;
  float* stats1 = (float*)(w + off); off += 512;
  float* stats2 = (float*)(w + off); off += 512;
  int*   oflc   = (int*)  (w + off); off += 16;
  int*   done1  = (int*)  (w + off); off += 16;
  int*   done2  = (int*)  (w + off); off += 16;
  size_t zbytes = off;               // everything above must start at 0
  float* dinv   = (float*)(w + off); off += (size_t)N * 4;
  float* scsh1  = (float*)(w + off); off += 512;
  float* scsh2  = (float*)(w + off); off += 512;
  int*   ofll   = (int*)  (w + off); off += (size_t)OCAP * 4;
  off = (off + 255) & ~(size_t)255;
  unsigned* pairs = (unsigned*)(w + off); off += (size_t)N * CAP * 4;
  __half* bufA  = (__half*)(w + off); off += (size_t)BN * 64 * 2;
  __half* bufB  = (__half*)(w + off); off += (size_t)BN * 64 * 2;

  float* out = (float*)d_out;

  hipMemsetAsync(w, 0, zbytes, stream);

  dim3 blk(256);
  int gB = (BN + 63) / 64;          // gemm blocks (layer 1)
  int fB = (E + 255) / 256;         // fill blocks
  int base3 = gB > (fB + 1) / 2 ? gB : (fB + 1) / 2;
  int gMega = 3 * base3;            // 1 gemm : 2 fill striping
  int gN  = (N + 255) / 256;
  int gR  = (BN + 3) / 4;
  int gA  = (N + 3) / 4;

  // ---- fill || layer-1 GEMM ----
  k_mega<<<gMega, blk, 0, stream>>>(x, W1, bufA, BN, N, ew, ei, cnt, pairs,
                                    oflc, ofll, E, gB, fB);
  k_degb<<<gA, blk, 0, stream>>>(pairs, cnt, dinv, N);
  k_dego<<<16, blk, 0, stream>>>(ew, ei, oflc, ofll, dinv, E);
  k_dinvf<<<gN, blk, 0, stream>>>(dinv, N);

  // ---- layer 1 agg + BN ----
  k_agg<<<gA, blk, 0, stream>>>(bufA, pairs, cnt, dinv, bufB, N);
  k_ofl<<<16, blk, 0, stream>>>(ew, ei, dinv, oflc, ofll, bufA, bufB, N, E);
  k_stats<<<400, blk, 0, stream>>>(bufB, b1, stats1, g1, be1, scsh1, done1,
                                   1.0f / (float)BN, BN);

  // ---- layer 2 ----
  k_gemm2<<<gB, blk, 0, stream>>>(bufB, W2, bufA, BN, b1, scsh1);
  k_agg<<<gA, blk, 0, stream>>>(bufA, pairs, cnt, dinv, bufB, N);
  k_ofl<<<16, blk, 0, stream>>>(ew, ei, dinv, oflc, ofll, bufA, bufB, N, E);
  k_stats<<<400, blk, 0, stream>>>(bufB, b2, stats2, g2, be2, scsh2, done2,
                                   1.0f / (float)BN, BN);

  // ---- head ----
  k_out<<<gR, blk, 0, stream>>>(bufB, b2, scsh2, Wc, bc, out, BN, N);
}